// Round 11
// baseline (256.135 us; speedup 1.0000x reference)
//
#include <hip/hip_runtime.h>
#include <math.h>

#define N_B 8192
#define N_K 64
#define DD  128
#define N_RELC 500
#define SLICES 8

// ---------------- Pass 1: group batch indices by relation (counting sort) ----------------
__global__ __launch_bounds__(1024) void sort_kernel(const int* __restrict__ r_idx,
                                                    const int* __restrict__ u_idx,
                                                    int* __restrict__ perm,
                                                    int* __restrict__ uperm,
                                                    int* __restrict__ offs)
{
    __shared__ int hist[512];
    __shared__ int scan[512];
    __shared__ int cur[512];
    const int t = threadIdx.x;
    if (t < 512) hist[t] = 0;
    __syncthreads();

    int rv[8];
#pragma unroll
    for (int k = 0; k < 8; ++k) {
        rv[k] = r_idx[t + 1024 * k];
        atomicAdd(&hist[rv[k]], 1);
    }
    __syncthreads();
    if (t < 512) scan[t] = hist[t];
    __syncthreads();
    for (int off = 1; off < 512; off <<= 1) {
        int v = 0;
        if (t < 512 && t >= off) v = scan[t - off];
        __syncthreads();
        if (t < 512) scan[t] += v;
        __syncthreads();
    }
    if (t < 512) {
        const int excl = scan[t] - hist[t];
        cur[t] = excl;
        if (t <= N_RELC) offs[t] = excl;   // offs[500] = 8192
    }
    __syncthreads();
#pragma unroll
    for (int k = 0; k < 8; ++k) {
        const int b   = t + 1024 * k;
        const int pos = atomicAdd(&cur[rv[k]], 1);
        perm[pos]  = b;
        uperm[pos] = u_idx[b];
    }
}

__device__ __forceinline__ float dot8(const float4 a0, const float4 a1,
                                      const float4 b0, const float4 b1) {
    float p = a0.x * b0.x;
    p = fmaf(a0.y, b0.y, p);
    p = fmaf(a0.z, b0.z, p);
    p = fmaf(a0.w, b0.w, p);
    p = fmaf(a1.x, b1.x, p);
    p = fmaf(a1.y, b1.y, p);
    p = fmaf(a1.z, b1.z, p);
    p = fmaf(a1.w, b1.w, p);
    return p;
}

__device__ __forceinline__ float red16(float p) {
    p += __shfl_xor(p, 1, 64);
    p += __shfl_xor(p, 2, 64);
    p += __shfl_xor(p, 4, 64);
    p += __shfl_xor(p, 8, 64);
    return p;
}

// ---------------- Pass 2: 4 b's per wg (one per wave), relation-grouped, XCD-pinned ----------------
// grid = 8 XCDs * 63 classes * 8 slices = 4032 wgs. Each W row load feeds 4 heads.
__global__ __launch_bounds__(256, 4) void hybo_main(
    const int* __restrict__ v_idx,
    const float* __restrict__ drug_entity, const float* __restrict__ target_entity,
    const float* __restrict__ relation_bias, const float* __restrict__ relation_transform,
    const float* __restrict__ bias_head, const float* __restrict__ bias_tail,
    const int* __restrict__ perm, const int* __restrict__ uperm,
    const int* __restrict__ offs,
    float* __restrict__ out)
{
    const int bid = blockIdx.x;
    const int x   = bid & 7;        // XCD
    const int i   = bid >> 3;       // 0..503
    const int rc  = i >> 3;         // relation class 0..62
    const int s   = i & 7;          // slice 0..7
    const int r   = (rc << 3) | x;
    if (r >= N_RELC) return;

    const int beg = offs[r];
    const int n   = offs[r + 1] - beg;
    if (s * 4 >= n) return;         // wg-uniform

    const int tid  = threadIdx.x;
    const int lane = tid & 63;
    const int w    = tid >> 6;      // wave id == b-slot
    const int q    = lane & 15;     // position within 16-lane group
    const int g    = lane >> 4;     // group id within wave (0..3)

    __shared__ float x_lds[4][DD];  // [b-slot][row]

    const float* Wb  = relation_transform + (size_t)r * (DD * DD);
    const float4 rb0 = *reinterpret_cast<const float4*>(relation_bias + r * DD + 8 * q);
    const float4 rb1 = *reinterpret_cast<const float4*>(relation_bias + r * DD + 8 * q + 4);

    for (int p0 = s * 4; p0 < n; p0 += SLICES * 4) {
        if (p0 != s * 4) __syncthreads();   // protect x_lds across group iterations

        // 4 u's for this group (clamped duplicates at relation tail)
        int uu[4];
#pragma unroll
        for (int j = 0; j < 4; ++j) {
            int p = p0 + j; if (p >= n) p = n - 1;
            uu[j] = uperm[beg + p];
        }
        const bool live = (p0 + w < n);
        const int  pw   = live ? (p0 + w) : (n - 1);
        const int  bw   = perm[beg + pw];          // this wave's b
        const float bh  = bias_head[uperm[beg + pw]];

        // all 16 v-indices for this wave's b (issued early, consumed in phase D)
        const int* vb = v_idx + (size_t)bw * N_K;
        int vi[16];
#pragma unroll
        for (int t = 0; t < 16; ++t) vi[t] = vb[t * 4 + g];

        // 4 heads
        float4 h0[4], h1[4];
#pragma unroll
        for (int j = 0; j < 4; ++j) {
            const float* hp = drug_entity + (size_t)uu[j] * DD + 8 * q;
            h0[j] = *reinterpret_cast<const float4*>(hp);
            h1[j] = *reinterpret_cast<const float4*>(hp + 4);
        }

        // ---- Phase B: rows [32w,32w+32), each W load feeds all 4 heads ----
#pragma unroll
        for (int ii = 0; ii < 8; ++ii) {
            const int e = w * 32 + ii * 4 + g;
            const float* row = Wb + e * DD + 8 * q;
            const float4 wv0 = *reinterpret_cast<const float4*>(row);
            const float4 wv1 = *reinterpret_cast<const float4*>(row + 4);
            float pa = dot8(wv0, wv1, h0[0], h1[0]);
            float pb = dot8(wv0, wv1, h0[1], h1[1]);
            float pc = dot8(wv0, wv1, h0[2], h1[2]);
            float pd = dot8(wv0, wv1, h0[3], h1[3]);
            pa = red16(pa); pb = red16(pb); pc = red16(pc); pd = red16(pd);
            if (q == 0) {
                x_lds[0][e] = pa; x_lds[1][e] = pb;
                x_lds[2][e] = pc; x_lds[3][e] = pd;
            }
        }

        // ---- prefetch tail block 0 before the barrier ----
        float4 t0A[4], t1A[4]; float btA[4];
#pragma unroll
        for (int ii2 = 0; ii2 < 4; ++ii2) {
            const float* trow = target_entity + (size_t)vi[ii2] * DD + 8 * q;
            t0A[ii2] = *reinterpret_cast<const float4*>(trow);
            t1A[ii2] = *reinterpret_cast<const float4*>(trow + 4);
            btA[ii2] = bias_tail[vi[ii2]];
        }

        __syncthreads();

        // ---- Phase C: wave-local (its own b = slot w) ----
        const float x0v = x_lds[w][0];              // pre-bias x[0] per reference
        float4 xa = *reinterpret_cast<const float4*>(&x_lds[w][8 * q]);
        float4 xb = *reinterpret_cast<const float4*>(&x_lds[w][8 * q + 4]);
        xa.x += rb0.x; xa.y += rb0.y; xa.z += rb0.z; xa.w += rb0.w;
        xb.x += rb1.x; xb.y += rb1.y; xb.z += rb1.z; xb.w += rb1.w;
        float sq = xa.y * xa.y + xa.z * xa.z + xa.w * xa.w
                 + xb.x * xb.x + xb.y * xb.y + xb.z * xb.z + xb.w * xb.w;
        if (q != 0) sq = fmaf(xa.x, xa.x, sq);      // exclude global element 0
        const float ssum  = red16(sq);
        const float timev = 2.5f / (1.0f + expf(-x0v)) + 1.1f;
        const float f     = sqrtf((timev * timev - 1.0f) / ssum);
        float4 ya, yb;
        ya.x = (q == 0) ? -timev : xa.x * f;
        ya.y = xa.y * f; ya.z = xa.z * f; ya.w = xa.w * f;
        yb.x = xb.x * f; yb.y = xb.y * f; yb.z = xb.z * f; yb.w = xb.w * f;

        // ---- Phase D: 64 tails, 4 blocks of 16, double-buffered prefetch ----
#define PREFETCH(T0, T1, BT, BLK)                                                   \
        {                                                                           \
            _Pragma("unroll")                                                       \
            for (int ii2 = 0; ii2 < 4; ++ii2) {                                     \
                const float* trow = target_entity + (size_t)vi[(BLK)*4+ii2] * DD + 8*q; \
                T0[ii2] = *reinterpret_cast<const float4*>(trow);                   \
                T1[ii2] = *reinterpret_cast<const float4*>(trow + 4);               \
                BT[ii2] = bias_tail[vi[(BLK)*4+ii2]];                               \
            }                                                                       \
        }
#define COMPUTE(T0, T1, BT, BLK)                                                    \
        {                                                                           \
            _Pragma("unroll")                                                       \
            for (int ii2 = 0; ii2 < 4; ++ii2) {                                     \
                float pd2 = dot8(T0[ii2], T1[ii2], ya, yb);                         \
                pd2 = red16(pd2);                                                   \
                if (live && q == 0)                                                 \
                    out[(size_t)bw * N_K + (BLK)*16 + ii2*4 + g] =                  \
                        fmaf(2.0f, pd2, 8.0f) + bh + BT[ii2];                       \
            }                                                                       \
        }

        float4 t0B[4], t1B[4]; float btB[4];
        PREFETCH(t0B, t1B, btB, 1)
        COMPUTE(t0A, t1A, btA, 0)
        PREFETCH(t0A, t1A, btA, 2)
        COMPUTE(t0B, t1B, btB, 1)
        PREFETCH(t0B, t1B, btB, 3)
        COMPUTE(t0A, t1A, btA, 2)
        COMPUTE(t0B, t1B, btB, 3)
#undef PREFETCH
#undef COMPUTE
    }
}

extern "C" void kernel_launch(void* const* d_in, const int* in_sizes, int n_in,
                              void* d_out, int out_size, void* d_ws, size_t ws_size,
                              hipStream_t stream) {
    const int*   u_idx  = (const int*)d_in[0];
    const int*   r_idx  = (const int*)d_in[1];
    const int*   v_idx  = (const int*)d_in[2];
    const float* drug   = (const float*)d_in[3];
    const float* targ   = (const float*)d_in[4];
    const float* rbias  = (const float*)d_in[5];
    const float* rtrans = (const float*)d_in[6];
    const float* bhead  = (const float*)d_in[7];
    const float* btail  = (const float*)d_in[8];
    float* out = (float*)d_out;

    int* perm  = (int*)d_ws;           // 8192 ints
    int* uperm = perm + N_B;           // 8192 ints
    int* offs  = uperm + N_B;          // 512 ints

    hipLaunchKernelGGL(sort_kernel, dim3(1), dim3(1024), 0, stream,
                       r_idx, u_idx, perm, uperm, offs);
    hipLaunchKernelGGL(hybo_main, dim3(8 * 63 * SLICES), dim3(256), 0, stream,
                       v_idx, drug, targ, rbias, rtrans, bhead, btail,
                       perm, uperm, offs, out);
}

// Round 13
// 218.967 us; speedup vs baseline: 1.1697x; 1.1697x over previous
//
#include <hip/hip_runtime.h>
#include <math.h>

#define N_B 8192
#define N_K 64
#define DD  128
#define N_RELC 500

// ---------------- Pass 1: group batch indices by relation (counting sort) ----------------
__global__ __launch_bounds__(1024) void sort_kernel(const int* __restrict__ r_idx,
                                                    const int* __restrict__ u_idx,
                                                    int* __restrict__ perm,
                                                    int* __restrict__ uperm,
                                                    int* __restrict__ offs)
{
    __shared__ int hist[512];
    __shared__ int scan[512];
    __shared__ int cur[512];
    const int t = threadIdx.x;
    if (t < 512) hist[t] = 0;
    __syncthreads();

    int rv[8];
#pragma unroll
    for (int k = 0; k < 8; ++k) {
        rv[k] = r_idx[t + 1024 * k];
        atomicAdd(&hist[rv[k]], 1);
    }
    __syncthreads();
    if (t < 512) scan[t] = hist[t];
    __syncthreads();
    for (int off = 1; off < 512; off <<= 1) {
        int v = 0;
        if (t < 512 && t >= off) v = scan[t - off];
        __syncthreads();
        if (t < 512) scan[t] += v;
        __syncthreads();
    }
    if (t < 512) {
        const int excl = scan[t] - hist[t];
        cur[t] = excl;
        if (t <= N_RELC) offs[t] = excl;   // offs[500] = 8192
    }
    __syncthreads();
#pragma unroll
    for (int k = 0; k < 8; ++k) {
        const int b   = t + 1024 * k;
        const int pos = atomicAdd(&cur[rv[k]], 1);
        perm[pos]  = b;
        uperm[pos] = u_idx[b];
    }
}

__device__ __forceinline__ float dot8(const float4 a0, const float4 a1,
                                      const float4 b0, const float4 b1) {
    float p = a0.x * b0.x;
    p = fmaf(a0.y, b0.y, p);
    p = fmaf(a0.z, b0.z, p);
    p = fmaf(a0.w, b0.w, p);
    p = fmaf(a1.x, b1.x, p);
    p = fmaf(a1.y, b1.y, p);
    p = fmaf(a1.z, b1.z, p);
    p = fmaf(a1.w, b1.w, p);
    return p;
}

__device__ __forceinline__ float red16(float p) {
    p += __shfl_xor(p, 1, 64);
    p += __shfl_xor(p, 2, 64);
    p += __shfl_xor(p, 4, 64);
    p += __shfl_xor(p, 8, 64);
    return p;
}

// ---------------- Pass 2: fully independent waves, zero barriers ----------------
// grid = 8 XCDs * 63 classes * 2 slices = 1008 wgs of 4 waves.
// Wave j (= slice*4 + wave) of relation r processes b-pairs {2j,2j+1}, {2j+16,...}.
// Pair shares W loads (halves W L2 traffic); everything wave-local; no __syncthreads.
__global__ __launch_bounds__(256) void hybo_main(
    const int* __restrict__ v_idx,
    const float* __restrict__ drug_entity, const float* __restrict__ target_entity,
    const float* __restrict__ relation_bias, const float* __restrict__ relation_transform,
    const float* __restrict__ bias_head, const float* __restrict__ bias_tail,
    const int* __restrict__ perm, const int* __restrict__ uperm,
    const int* __restrict__ offs,
    float* __restrict__ out)
{
    const int bid = blockIdx.x;
    const int x   = bid & 7;        // XCD
    const int i   = bid >> 3;       // 0..125
    const int rc  = i >> 1;         // relation class 0..62
    const int s   = i & 1;          // slice 0..1
    const int r   = (rc << 3) | x;
    if (r >= N_RELC) return;

    const int beg = offs[r];
    const int n   = offs[r + 1] - beg;

    const int tid  = threadIdx.x;
    const int lane = tid & 63;
    const int w    = tid >> 6;      // wave id in wg
    const int q    = lane & 15;     // position within 16-lane group
    const int g    = lane >> 4;     // group id within wave (0..3)
    const int j    = s * 4 + w;     // wave slot 0..7 within relation

    __shared__ float x_lds[4][2][DD];   // [wave][pair-slot][dim], 4 KB

    const float4 rb0 = *reinterpret_cast<const float4*>(relation_bias + r * DD + 8 * q);
    const float4 rb1 = *reinterpret_cast<const float4*>(relation_bias + r * DD + 8 * q + 4);
    const float* Wb  = relation_transform + (size_t)r * (DD * DD);

    for (int pb = 2 * j; pb < n; pb += 16) {
        const bool has1 = (pb + 1 < n);
        const int  p1   = has1 ? pb + 1 : pb;
        const int  b0   = perm[beg + pb],  b1 = perm[beg + p1];
        const int  u0   = uperm[beg + pb], u1 = uperm[beg + p1];
        const float bh0 = bias_head[u0],   bh1 = bias_head[u1];

        const float* hp0 = drug_entity + (size_t)u0 * DD + 8 * q;
        const float* hp1 = drug_entity + (size_t)u1 * DD + 8 * q;
        const float4 ha0 = *reinterpret_cast<const float4*>(hp0);
        const float4 ha1 = *reinterpret_cast<const float4*>(hp0 + 4);
        const float4 hb0 = *reinterpret_cast<const float4*>(hp1);
        const float4 hb1 = *reinterpret_cast<const float4*>(hp1 + 4);

        // ---- Phase B: all 128 rows by this wave, 4 rows/iter, shared W for both b's ----
#pragma unroll 4
        for (int it = 0; it < 32; ++it) {
            const int e = it * 4 + g;
            const float* row = Wb + e * DD + 8 * q;
            const float4 wv0 = *reinterpret_cast<const float4*>(row);
            const float4 wv1 = *reinterpret_cast<const float4*>(row + 4);
            float pa = dot8(wv0, wv1, ha0, ha1);
            float pc = dot8(wv0, wv1, hb0, hb1);
            pa = red16(pa); pc = red16(pc);
            if (q == 0) { x_lds[w][0][e] = pa; x_lds[w][1][e] = pc; }
        }
        // Same-wave LDS write->read: ordered by lgkmcnt, no barrier needed.

        // ---- Phase C + D per pair slot (statically unrolled) ----
#pragma unroll
        for (int ps = 0; ps < 2; ++ps) {
            const int   bw = ps ? b1 : b0;
            const float bh = ps ? bh1 : bh0;
            const bool  wr = (ps == 0) || has1;

            const float x0v = x_lds[w][ps][0];          // pre-bias x[0] per reference
            float4 xa = *reinterpret_cast<const float4*>(&x_lds[w][ps][8 * q]);
            float4 xb = *reinterpret_cast<const float4*>(&x_lds[w][ps][8 * q + 4]);
            xa.x += rb0.x; xa.y += rb0.y; xa.z += rb0.z; xa.w += rb0.w;
            xb.x += rb1.x; xb.y += rb1.y; xb.z += rb1.z; xb.w += rb1.w;
            float sq = xa.y * xa.y + xa.z * xa.z + xa.w * xa.w
                     + xb.x * xb.x + xb.y * xb.y + xb.z * xb.z + xb.w * xb.w;
            if (q != 0) sq = fmaf(xa.x, xa.x, sq);      // exclude global element 0
            const float ssum  = red16(sq);
            const float timev = 2.5f / (1.0f + expf(-x0v)) + 1.1f;
            const float f     = sqrtf((timev * timev - 1.0f) / ssum);
            float4 ya, yb;
            ya.x = (q == 0) ? -timev : xa.x * f;
            ya.y = xa.y * f; ya.z = xa.z * f; ya.w = xa.w * f;
            yb.x = xb.x * f; yb.y = xb.y * f; yb.z = xb.z * f; yb.w = xb.w * f;

            const int* vb = v_idx + (size_t)bw * N_K;
            // ---- Phase D: 16 blocks x 4 tails (one per 16-lane group) ----
#pragma unroll 4
            for (int blk = 0; blk < 16; ++blk) {
                const int vi = vb[blk * 4 + g];
                const float* trow = target_entity + (size_t)vi * DD + 8 * q;
                const float4 t0 = *reinterpret_cast<const float4*>(trow);
                const float4 t1 = *reinterpret_cast<const float4*>(trow + 4);
                const float bt = bias_tail[vi];
                float pd = dot8(t0, t1, ya, yb);
                pd = red16(pd);
                if (q == 0 && wr)
                    out[(size_t)bw * N_K + blk * 4 + g] = fmaf(2.0f, pd, 8.0f) + bh + bt;
            }
        }
    }
}

extern "C" void kernel_launch(void* const* d_in, const int* in_sizes, int n_in,
                              void* d_out, int out_size, void* d_ws, size_t ws_size,
                              hipStream_t stream) {
    const int*   u_idx  = (const int*)d_in[0];
    const int*   r_idx  = (const int*)d_in[1];
    const int*   v_idx  = (const int*)d_in[2];
    const float* drug   = (const float*)d_in[3];
    const float* targ   = (const float*)d_in[4];
    const float* rbias  = (const float*)d_in[5];
    const float* rtrans = (const float*)d_in[6];
    const float* bhead  = (const float*)d_in[7];
    const float* btail  = (const float*)d_in[8];
    float* out = (float*)d_out;

    int* perm  = (int*)d_ws;           // 8192 ints
    int* uperm = perm + N_B;           // 8192 ints
    int* offs  = uperm + N_B;          // 512 ints

    hipLaunchKernelGGL(sort_kernel, dim3(1), dim3(1024), 0, stream,
                       r_idx, u_idx, perm, uperm, offs);
    hipLaunchKernelGGL(hybo_main, dim3(8 * 63 * 2), dim3(256), 0, stream,
                       v_idx, drug, targ, rbias, rtrans, bhead, btail,
                       perm, uperm, offs, out);
}

// Round 15
// 173.685 us; speedup vs baseline: 1.4747x; 1.2607x over previous
//
#include <hip/hip_runtime.h>
#include <math.h>

#define N_B 8192
#define N_K 64
#define DD  128
#define N_RELC 500
#define KMAX 1536   // slots per XCD class (expected ~1030, huge margin)

// ---- Pass 1: counting sort by relation + per-XCD-class slot map ----
__global__ __launch_bounds__(1024) void sort_kernel(const int* __restrict__ r_idx,
                                                    const int* __restrict__ u_idx,
                                                    int* __restrict__ perm,
                                                    int* __restrict__ uperm,
                                                    int* __restrict__ rperm,
                                                    int* __restrict__ slotmap,
                                                    int* __restrict__ cls_total)
{
    __shared__ int hist[512];
    __shared__ int scan[512];   // full inclusive scan
    __shared__ int scan8[512];  // per-class (stride-8) inclusive scan
    __shared__ int cur[512];
    const int t = threadIdx.x;
    if (t < 512) hist[t] = 0;
    __syncthreads();

    int rv[8];
#pragma unroll
    for (int k = 0; k < 8; ++k) {
        rv[k] = r_idx[t + 1024 * k];
        atomicAdd(&hist[rv[k]], 1);
    }
    __syncthreads();
    if (t < 512) { scan[t] = hist[t]; scan8[t] = hist[t]; }
    __syncthreads();
    for (int off = 1; off < 512; off <<= 1) {
        int v = 0;
        if (t < 512 && t >= off) v = scan[t - off];
        __syncthreads();
        if (t < 512) scan[t] += v;
        __syncthreads();
    }
    for (int off = 8; off < 512; off <<= 1) {
        int v = 0;
        if (t < 512 && t >= off) v = scan8[t - off];
        __syncthreads();
        if (t < 512) scan8[t] += v;
        __syncthreads();
    }
    if (t < 512) cur[t] = scan[t] - hist[t];     // exclusive (relation start)
    if (t < 8) {
        const int last = t + 8 * ((N_RELC - 1 - t) >> 3);  // last relation in class t
        cls_total[t] = scan8[last];
    }
    __syncthreads();
#pragma unroll
    for (int k = 0; k < 8; ++k) {
        const int b   = t + 1024 * k;
        const int r   = rv[k];
        const int pos = atomicAdd(&cur[r], 1);
        perm[pos]  = b;
        uperm[pos] = u_idx[b];
        rperm[pos] = r;
        const int p    = pos - (scan[r] - hist[r]);       // index within relation
        const int slot = (scan8[r] - hist[r]) + p;        // class-wide slot
        slotmap[8 * slot + (r & 7)] = pos;
    }
}

// ---- Pass 2: one b per 256-thread wg (round-6 body), XCD-pinned via slotmap ----
__global__ __launch_bounds__(256) void hybo_main(
    const int* __restrict__ v_idx,
    const float* __restrict__ drug_entity, const float* __restrict__ target_entity,
    const float* __restrict__ relation_bias, const float* __restrict__ relation_transform,
    const float* __restrict__ bias_head, const float* __restrict__ bias_tail,
    const int* __restrict__ perm, const int* __restrict__ uperm,
    const int* __restrict__ rperm, const int* __restrict__ slotmap,
    const int* __restrict__ cls_total,
    float* __restrict__ out)
{
    const int bid = blockIdx.x;
    const int x   = bid & 7;          // XCD class
    const int k   = bid >> 3;         // slot within class
    if (k >= cls_total[x]) return;    // wg-uniform exit

    const int pos = slotmap[bid];
    const int b   = perm[pos];
    const int u   = uperm[pos];
    const int r   = rperm[pos];

    const int tid  = threadIdx.x;
    const int lane = tid & 63;
    const int wave = tid >> 6;
    const int q    = lane & 15;       // position within 16-lane group
    const int g    = lane >> 4;       // group id within wave (0..3)

    __shared__ float x_lds[DD];
    __shared__ float y_lds[DD];
    __shared__ float red_lds[4];

    // v indices for phase D
    int vi[4];
#pragma unroll
    for (int i = 0; i < 4; ++i)
        vi[i] = v_idx[(size_t)b * N_K + wave * 16 + i * 4 + g];

    // head slice: head[8q .. 8q+7]
    const float4 h0 = *reinterpret_cast<const float4*>(drug_entity + (size_t)u * DD + 8 * q);
    const float4 h1 = *reinterpret_cast<const float4*>(drug_entity + (size_t)u * DD + 8 * q + 4);

    // ---- Phase B: x[e] = dot(W[e,:], head); wave owns rows [32w,32w+32) ----
    const float* Wb = relation_transform + (size_t)r * DD * DD;
    float4 wv[16];
#pragma unroll
    for (int i = 0; i < 8; ++i) {
        const float* row = Wb + (wave * 32 + i * 4 + g) * DD + 8 * q;
        wv[2 * i]     = *reinterpret_cast<const float4*>(row);
        wv[2 * i + 1] = *reinterpret_cast<const float4*>(row + 4);
    }
#pragma unroll
    for (int i = 0; i < 8; ++i) {
        float p;
        p = wv[2 * i].x * h0.x;
        p = fmaf(wv[2 * i].y,     h0.y, p);
        p = fmaf(wv[2 * i].z,     h0.z, p);
        p = fmaf(wv[2 * i].w,     h0.w, p);
        p = fmaf(wv[2 * i + 1].x, h1.x, p);
        p = fmaf(wv[2 * i + 1].y, h1.y, p);
        p = fmaf(wv[2 * i + 1].z, h1.z, p);
        p = fmaf(wv[2 * i + 1].w, h1.w, p);
        p += __shfl_xor(p, 1, 64);
        p += __shfl_xor(p, 2, 64);
        p += __shfl_xor(p, 4, 64);
        p += __shfl_xor(p, 8, 64);
        if (q == 0) x_lds[wave * 32 + i * 4 + g] = p;
    }

    // ---- issue phase-D tail loads now; latency hides under phase C ----
    float4 t0[4], t1[4];
    float  bt[4];
#pragma unroll
    for (int i = 0; i < 4; ++i) {
        const float* trow = target_entity + (size_t)vi[i] * DD + 8 * q;
        t0[i] = *reinterpret_cast<const float4*>(trow);
        t1[i] = *reinterpret_cast<const float4*>(trow + 4);
        bt[i] = bias_tail[vi[i]];
    }

    __syncthreads();

    // ---- Phase C: time, norm factor ----
    const float x0 = x_lds[0];            // pre-bias x[0] per reference
    float xv = 0.0f, sq = 0.0f;
    if (tid < DD) {
        xv = x_lds[tid] + relation_bias[(size_t)r * DD + tid];
        y_lds[tid] = xv;
        if (tid > 0) sq = xv * xv;        // nar = x[1:]
    }
    float ps = sq;
#pragma unroll
    for (int m = 32; m >= 1; m >>= 1) ps += __shfl_xor(ps, m, 64);
    if (lane == 0) red_lds[wave] = ps;
    __syncthreads();

    const float timev = 2.5f / (1.0f + expf(-x0)) + 1.1f;
    const float s = red_lds[0] + red_lds[1] + red_lds[2] + red_lds[3];
    const float f = sqrtf((timev * timev - 1.0f) / s);

    // y[0] = -time, y[j] = xv[j]*f; cin = dot(y, tail)
    float4 ya = *reinterpret_cast<const float4*>(&y_lds[8 * q]);
    float4 yb = *reinterpret_cast<const float4*>(&y_lds[8 * q + 4]);
    ya.x = (q == 0) ? -timev : ya.x * f;
    ya.y *= f; ya.z *= f; ya.w *= f;
    yb.x *= f; yb.y *= f; yb.z *= f; yb.w *= f;

    const float bh = bias_head[u];

    // ---- Phase D: 16 tails per wave, 4 per iter (one per group) ----
#pragma unroll
    for (int i = 0; i < 4; ++i) {
        float p;
        p = t0[i].x * ya.x;
        p = fmaf(t0[i].y, ya.y, p);
        p = fmaf(t0[i].z, ya.z, p);
        p = fmaf(t0[i].w, ya.w, p);
        p = fmaf(t1[i].x, yb.x, p);
        p = fmaf(t1[i].y, yb.y, p);
        p = fmaf(t1[i].z, yb.z, p);
        p = fmaf(t1[i].w, yb.w, p);
        p += __shfl_xor(p, 1, 64);
        p += __shfl_xor(p, 2, 64);
        p += __shfl_xor(p, 4, 64);
        p += __shfl_xor(p, 8, 64);
        if (q == 0)
            out[(size_t)b * N_K + wave * 16 + i * 4 + g] = fmaf(2.0f, p, 8.0f) + bh + bt[i];
    }
}

extern "C" void kernel_launch(void* const* d_in, const int* in_sizes, int n_in,
                              void* d_out, int out_size, void* d_ws, size_t ws_size,
                              hipStream_t stream) {
    const int*   u_idx  = (const int*)d_in[0];
    const int*   r_idx  = (const int*)d_in[1];
    const int*   v_idx  = (const int*)d_in[2];
    const float* drug   = (const float*)d_in[3];
    const float* targ   = (const float*)d_in[4];
    const float* rbias  = (const float*)d_in[5];
    const float* rtrans = (const float*)d_in[6];
    const float* bhead  = (const float*)d_in[7];
    const float* btail  = (const float*)d_in[8];
    float* out = (float*)d_out;

    int* perm     = (int*)d_ws;                 // 8192
    int* uperm    = perm + N_B;                 // 8192
    int* rperm    = uperm + N_B;                // 8192
    int* slotmap  = rperm + N_B;                // 8*KMAX = 12288
    int* cls      = slotmap + 8 * KMAX;         // 8

    hipLaunchKernelGGL(sort_kernel, dim3(1), dim3(1024), 0, stream,
                       r_idx, u_idx, perm, uperm, rperm, slotmap, cls);
    hipLaunchKernelGGL(hybo_main, dim3(8 * KMAX), dim3(256), 0, stream,
                       v_idx, drug, targ, rbias, rtrans, bhead, btail,
                       perm, uperm, rperm, slotmap, cls, out);
}

// Round 17
// 173.384 us; speedup vs baseline: 1.4773x; 1.0017x over previous
//
#include <hip/hip_runtime.h>
#include <math.h>

#define N_B 8192
#define N_K 64
#define DD  128
#define N_RELC 500
#define KMAX 1536   // slots per XCD class (expected ~1030, huge margin)

// ---- Pass 1: counting sort by relation + per-XCD-class slot map ----
__global__ __launch_bounds__(1024) void sort_kernel(const int* __restrict__ r_idx,
                                                    const int* __restrict__ u_idx,
                                                    int* __restrict__ perm,
                                                    int* __restrict__ uperm,
                                                    int* __restrict__ rperm,
                                                    int* __restrict__ slotmap,
                                                    int* __restrict__ cls_total)
{
    __shared__ int hist[512];
    __shared__ int scan[512];   // full inclusive scan
    __shared__ int scan8[512];  // per-class (stride-8) inclusive scan
    __shared__ int cur[512];
    const int t = threadIdx.x;
    if (t < 512) hist[t] = 0;
    __syncthreads();

    int rv[8];
#pragma unroll
    for (int k = 0; k < 8; ++k) {
        rv[k] = r_idx[t + 1024 * k];
        atomicAdd(&hist[rv[k]], 1);
    }
    __syncthreads();
    if (t < 512) { scan[t] = hist[t]; scan8[t] = hist[t]; }
    __syncthreads();
    for (int off = 1; off < 512; off <<= 1) {
        int v = 0;
        if (t < 512 && t >= off) v = scan[t - off];
        __syncthreads();
        if (t < 512) scan[t] += v;
        __syncthreads();
    }
    for (int off = 8; off < 512; off <<= 1) {
        int v = 0;
        if (t < 512 && t >= off) v = scan8[t - off];
        __syncthreads();
        if (t < 512) scan8[t] += v;
        __syncthreads();
    }
    if (t < 512) cur[t] = scan[t] - hist[t];     // exclusive (relation start)
    if (t < 8) {
        const int last = t + 8 * ((N_RELC - 1 - t) >> 3);  // last relation in class t
        cls_total[t] = scan8[last];
    }
    __syncthreads();
#pragma unroll
    for (int k = 0; k < 8; ++k) {
        const int b   = t + 1024 * k;
        const int r   = rv[k];
        const int pos = atomicAdd(&cur[r], 1);
        perm[pos]  = b;
        uperm[pos] = u_idx[b];
        rperm[pos] = r;
        const int p    = pos - (scan[r] - hist[r]);       // index within relation
        const int slot = (scan8[r] - hist[r]) + p;        // class-wide slot
        slotmap[8 * slot + (r & 7)] = pos;
    }
}

// ---- Pass 2: one b per 256-thread wg, XCD-pinned via slotmap ----
// __launch_bounds__(256, 1): min 1 wave/EU -> allocator may use up to 256 VGPRs,
// so wv[16] (64 VGPR) + tail prefetch (48 VGPR) stay resident -> real MLP.
// (Round 15 identical code at default bounds: VGPR=52, loads folded, 62 us.)
__global__ __launch_bounds__(256, 1) void hybo_main(
    const int* __restrict__ v_idx,
    const float* __restrict__ drug_entity, const float* __restrict__ target_entity,
    const float* __restrict__ relation_bias, const float* __restrict__ relation_transform,
    const float* __restrict__ bias_head, const float* __restrict__ bias_tail,
    const int* __restrict__ perm, const int* __restrict__ uperm,
    const int* __restrict__ rperm, const int* __restrict__ slotmap,
    const int* __restrict__ cls_total,
    float* __restrict__ out)
{
    const int bid = blockIdx.x;
    const int x   = bid & 7;          // XCD class
    const int k   = bid >> 3;         // slot within class
    if (k >= cls_total[x]) return;    // wg-uniform exit

    const int pos = slotmap[bid];
    const int b   = perm[pos];
    const int u   = uperm[pos];
    const int r   = rperm[pos];

    const int tid  = threadIdx.x;
    const int lane = tid & 63;
    const int wave = tid >> 6;
    const int q    = lane & 15;       // position within 16-lane group
    const int g    = lane >> 4;       // group id within wave (0..3)

    __shared__ float x_lds[DD];
    __shared__ float y_lds[DD];
    __shared__ float red_lds[4];

    // v indices for phase D
    int vi[4];
#pragma unroll
    for (int i = 0; i < 4; ++i)
        vi[i] = v_idx[(size_t)b * N_K + wave * 16 + i * 4 + g];

    // head slice: head[8q .. 8q+7]
    const float4 h0 = *reinterpret_cast<const float4*>(drug_entity + (size_t)u * DD + 8 * q);
    const float4 h1 = *reinterpret_cast<const float4*>(drug_entity + (size_t)u * DD + 8 * q + 4);

    // ---- Phase B: x[e] = dot(W[e,:], head); wave owns rows [32w,32w+32) ----
    const float* Wb = relation_transform + (size_t)r * DD * DD;
    float4 wv[16];
#pragma unroll
    for (int i = 0; i < 8; ++i) {
        const float* row = Wb + (wave * 32 + i * 4 + g) * DD + 8 * q;
        wv[2 * i]     = *reinterpret_cast<const float4*>(row);
        wv[2 * i + 1] = *reinterpret_cast<const float4*>(row + 4);
    }
#pragma unroll
    for (int i = 0; i < 8; ++i) {
        float p;
        p = wv[2 * i].x * h0.x;
        p = fmaf(wv[2 * i].y,     h0.y, p);
        p = fmaf(wv[2 * i].z,     h0.z, p);
        p = fmaf(wv[2 * i].w,     h0.w, p);
        p = fmaf(wv[2 * i + 1].x, h1.x, p);
        p = fmaf(wv[2 * i + 1].y, h1.y, p);
        p = fmaf(wv[2 * i + 1].z, h1.z, p);
        p = fmaf(wv[2 * i + 1].w, h1.w, p);
        p += __shfl_xor(p, 1, 64);
        p += __shfl_xor(p, 2, 64);
        p += __shfl_xor(p, 4, 64);
        p += __shfl_xor(p, 8, 64);
        if (q == 0) x_lds[wave * 32 + i * 4 + g] = p;
    }

    // ---- issue phase-D tail loads now; latency hides under phase C ----
    float4 t0[4], t1[4];
    float  bt[4];
#pragma unroll
    for (int i = 0; i < 4; ++i) {
        const float* trow = target_entity + (size_t)vi[i] * DD + 8 * q;
        t0[i] = *reinterpret_cast<const float4*>(trow);
        t1[i] = *reinterpret_cast<const float4*>(trow + 4);
        bt[i] = bias_tail[vi[i]];
    }

    __syncthreads();

    // ---- Phase C: time, norm factor ----
    const float x0 = x_lds[0];            // pre-bias x[0] per reference
    float xv = 0.0f, sq = 0.0f;
    if (tid < DD) {
        xv = x_lds[tid] + relation_bias[(size_t)r * DD + tid];
        y_lds[tid] = xv;
        if (tid > 0) sq = xv * xv;        // nar = x[1:]
    }
    float ps = sq;
#pragma unroll
    for (int m = 32; m >= 1; m >>= 1) ps += __shfl_xor(ps, m, 64);
    if (lane == 0) red_lds[wave] = ps;
    __syncthreads();

    const float timev = 2.5f / (1.0f + expf(-x0)) + 1.1f;
    const float s = red_lds[0] + red_lds[1] + red_lds[2] + red_lds[3];
    const float f = sqrtf((timev * timev - 1.0f) / s);

    // y[0] = -time, y[j] = xv[j]*f; cin = dot(y, tail)
    float4 ya = *reinterpret_cast<const float4*>(&y_lds[8 * q]);
    float4 yb = *reinterpret_cast<const float4*>(&y_lds[8 * q + 4]);
    ya.x = (q == 0) ? -timev : ya.x * f;
    ya.y *= f; ya.z *= f; ya.w *= f;
    yb.x *= f; yb.y *= f; yb.z *= f; yb.w *= f;

    const float bh = bias_head[u];

    // ---- Phase D: 16 tails per wave, 4 per iter (one per group) ----
#pragma unroll
    for (int i = 0; i < 4; ++i) {
        float p;
        p = t0[i].x * ya.x;
        p = fmaf(t0[i].y, ya.y, p);
        p = fmaf(t0[i].z, ya.z, p);
        p = fmaf(t0[i].w, ya.w, p);
        p = fmaf(t1[i].x, yb.x, p);
        p = fmaf(t1[i].y, yb.y, p);
        p = fmaf(t1[i].z, yb.z, p);
        p = fmaf(t1[i].w, yb.w, p);
        p += __shfl_xor(p, 1, 64);
        p += __shfl_xor(p, 2, 64);
        p += __shfl_xor(p, 4, 64);
        p += __shfl_xor(p, 8, 64);
        if (q == 0)
            out[(size_t)b * N_K + wave * 16 + i * 4 + g] = fmaf(2.0f, p, 8.0f) + bh + bt[i];
    }
}

extern "C" void kernel_launch(void* const* d_in, const int* in_sizes, int n_in,
                              void* d_out, int out_size, void* d_ws, size_t ws_size,
                              hipStream_t stream) {
    const int*   u_idx  = (const int*)d_in[0];
    const int*   r_idx  = (const int*)d_in[1];
    const int*   v_idx  = (const int*)d_in[2];
    const float* drug   = (const float*)d_in[3];
    const float* targ   = (const float*)d_in[4];
    const float* rbias  = (const float*)d_in[5];
    const float* rtrans = (const float*)d_in[6];
    const float* bhead  = (const float*)d_in[7];
    const float* btail  = (const float*)d_in[8];
    float* out = (float*)d_out;

    int* perm     = (int*)d_ws;                 // 8192
    int* uperm    = perm + N_B;                 // 8192
    int* rperm    = uperm + N_B;                // 8192
    int* slotmap  = rperm + N_B;                // 8*KMAX = 12288
    int* cls      = slotmap + 8 * KMAX;         // 8

    hipLaunchKernelGGL(sort_kernel, dim3(1), dim3(1024), 0, stream,
                       r_idx, u_idx, perm, uperm, rperm, slotmap, cls);
    hipLaunchKernelGGL(hybo_main, dim3(8 * KMAX), dim3(256), 0, stream,
                       v_idx, drug, targ, rbias, rtrans, bhead, btail,
                       perm, uperm, rperm, slotmap, cls, out);
}